// Round 1
// baseline (170.285 us; speedup 1.0000x reference)
//
#include <hip/hip_runtime.h>

// VDP dropout:
//   keep      = (u >= 0.1f)
//   mu_out    = mu_in    * keep / 0.9
//   Sigma_out = Sigma_in * keep / 768     (D = last-dim size)
//
// Elementwise over N = B*T*D = 64*197*768 = 9,683,968 fp32 elements.
// Memory-bound: 3 reads + 2 writes per element = 20 B/elem ≈ 194 MB total.
// float4 vectorization; N % 4 == 0 and N % 256 == 0, so no tail handling.

#define DROP_PROP 0.1f

__global__ __launch_bounds__(256) void vdp_dropout_kernel(
    const float4* __restrict__ mu_in,
    const float4* __restrict__ sigma_in,
    const float4* __restrict__ u,
    float4* __restrict__ mu_out,
    float4* __restrict__ sigma_out,
    int n4)
{
    const float inv_keep = 1.0f / (1.0f - DROP_PROP);   // 1/0.9
    const float inv_d    = 1.0f / 768.0f;

    int i = blockIdx.x * blockDim.x + threadIdx.x;
    if (i >= n4) return;

    float4 uu = u[i];
    float4 m  = mu_in[i];
    float4 s  = sigma_in[i];

    float4 mo, so;
    mo.x = (uu.x >= DROP_PROP) ? m.x * inv_keep : 0.0f;
    mo.y = (uu.y >= DROP_PROP) ? m.y * inv_keep : 0.0f;
    mo.z = (uu.z >= DROP_PROP) ? m.z * inv_keep : 0.0f;
    mo.w = (uu.w >= DROP_PROP) ? m.w * inv_keep : 0.0f;

    so.x = (uu.x >= DROP_PROP) ? s.x * inv_d : 0.0f;
    so.y = (uu.y >= DROP_PROP) ? s.y * inv_d : 0.0f;
    so.z = (uu.z >= DROP_PROP) ? s.z * inv_d : 0.0f;
    so.w = (uu.w >= DROP_PROP) ? s.w * inv_d : 0.0f;

    mu_out[i]    = mo;
    sigma_out[i] = so;
}

extern "C" void kernel_launch(void* const* d_in, const int* in_sizes, int n_in,
                              void* d_out, int out_size, void* d_ws, size_t ws_size,
                              hipStream_t stream)
{
    const float* mu_in    = (const float*)d_in[0];
    const float* sigma_in = (const float*)d_in[1];
    const float* u        = (const float*)d_in[2];

    const int n = in_sizes[0];          // 9,683,968
    float* mu_out    = (float*)d_out;           // first n elements
    float* sigma_out = (float*)d_out + n;       // next n elements

    const int n4 = n / 4;               // n % 4 == 0
    const int block = 256;
    const int grid = (n4 + block - 1) / block;

    vdp_dropout_kernel<<<grid, block, 0, stream>>>(
        (const float4*)mu_in, (const float4*)sigma_in, (const float4*)u,
        (float4*)mu_out, (float4*)sigma_out, n4);
}